// Round 5
// baseline (408.824 us; speedup 1.0000x reference)
//
#include <hip/hip_runtime.h>

typedef short bf16x8 __attribute__((ext_vector_type(8)));
typedef float f32x4  __attribute__((ext_vector_type(4)));
typedef unsigned int u32x2 __attribute__((ext_vector_type(2)));

#define B_SZ   2
#define T_SZ   2048
#define N_SZ   2048
#define HID_SZ 1024
#define NHEADS 16

// scale/sqrt(half) * log2(e), folded into Q at projection epilogue
#define SLOG2E 0.25500297f

static __device__ __forceinline__ float fexp2(float x) {
#if __has_builtin(__builtin_amdgcn_exp2f)
    return __builtin_amdgcn_exp2f(x);       // raw v_exp_f32
#else
    float r; __asm__("v_exp_f32 %0, %1" : "=v"(r) : "v"(x)); return r;
#endif
}

static __device__ __forceinline__ short f2bf(float f) {
    unsigned u = __float_as_uint(f);
    u = (u + 0x7fffu + ((u >> 16) & 1u)) >> 16;   // RNE
    return (short)u;
}

// pack two floats -> two bf16 (round-half-up) via v_perm_b32: 3 VALU ops
static __device__ __forceinline__ unsigned pk2(float a, float b) {
#if __has_builtin(__builtin_amdgcn_perm)
    return __builtin_amdgcn_perm(__float_as_uint(b) + 0x8000u,
                                 __float_as_uint(a) + 0x8000u, 0x07060302u);
#else
    unsigned ua = (__float_as_uint(a) + 0x8000u) >> 16;
    unsigned ub = (__float_as_uint(b) + 0x8000u) & 0xffff0000u;
    return ua | ub;
#endif
}

// async global->LDS, 16B per lane; LDS dest = wave-uniform base + lane*16
static __device__ __forceinline__ void gload16(const void* g, void* l) {
    __builtin_amdgcn_global_load_lds(
        (const __attribute__((address_space(1))) unsigned int*)g,
        (__attribute__((address_space(3))) unsigned int*)l, 16, 0, 0);
}

#define MFMA16(a, b, c) __builtin_amdgcn_mfma_f32_16x16x32_bf16((a), (b), (c), 0, 0, 0)

// ---------------------------------------------------------------------------
// fp32 -> bf16 pre-convert (RNE), 8 elem/thread.
// ---------------------------------------------------------------------------
__global__ __launch_bounds__(256) void cvt_kernel(
    const float* __restrict__ dec, const float* __restrict__ enc,
    const float* __restrict__ Wq, const float* __restrict__ Wk,
    const float* __restrict__ Wv,
    short* __restrict__ decb, short* __restrict__ encb,
    short* __restrict__ wqb, short* __restrict__ wkb, short* __restrict__ wvb)
{
    const float* src; short* dst; int n;
    switch (blockIdx.y) {
      case 0: src = dec; dst = decb; n = B_SZ * T_SZ * HID_SZ; break;
      case 1: src = enc; dst = encb; n = B_SZ * N_SZ * HID_SZ; break;
      case 2: src = Wq;  dst = wqb;  n = HID_SZ * HID_SZ;      break;
      case 3: src = Wk;  dst = wkb;  n = HID_SZ * HID_SZ;      break;
      default:src = Wv;  dst = wvb;  n = HID_SZ * HID_SZ;      break;
    }
    const int idx = (blockIdx.x * 256 + threadIdx.x) * 8;
    if (idx >= n) return;
    float4 a = *(const float4*)&src[idx];
    float4 b = *(const float4*)&src[idx + 4];
    bf16x8 r;
    r[0]=f2bf(a.x); r[1]=f2bf(a.y); r[2]=f2bf(a.z); r[3]=f2bf(a.w);
    r[4]=f2bf(b.x); r[5]=f2bf(b.y); r[6]=f2bf(b.z); r[7]=f2bf(b.w);
    *(bf16x8*)&dst[idx] = r;
}

// ---------------------------------------------------------------------------
// Projection GEMM, m97 structure + XOR-swizzled staging (conflict fix).
// 128x128 tile, BK=64, 256 thr = 4 waves (2x2), 64x64/wave.
// LDS tile [128 rows][8 kgroups of 16B]; LDS kgroup g holds global kgroup
// g ^ (row & 7)  (permuted on the global-address side of global_load_lds so
// the LDS destination stays lane-contiguous as the HW requires).
// Fragment reads un-permute with ^(r16&7) -> 2-way bank aliasing (free).
// ---------------------------------------------------------------------------
__global__ __launch_bounds__(256) void proj_kernel(
    const short* __restrict__ decb, const short* __restrict__ encb,
    const short* __restrict__ wqb, const short* __restrict__ wkb,
    const short* __restrict__ wvb,
    short* __restrict__ qbuf, short* __restrict__ kbuf, short* __restrict__ vT)
{
    const int i    = blockIdx.x;
    const int work = (i & 7) * 96 + (i >> 3);     // XCD-contiguous work id
    const int proj = work >> 8;
    const int rem  = work & 255;
    const int c0   = (rem >> 5) * 128;
    const int m0   = (rem & 31) * 128;

    const short* __restrict__ X = (proj == 0) ? decb : encb;
    const short* __restrict__ W = (proj == 0) ? wqb : ((proj == 1) ? wkb : wvb);

    __shared__ short As[128 * 64];   // 16 KB
    __shared__ short Bs[128 * 64];   // 16 KB

    const int tid  = threadIdx.x;
    const int lane = tid & 63;
    const int w    = tid >> 6;
    const int wm   = (w >> 1) * 64;
    const int wn   = (w & 1) * 64;
    const int q4   = lane >> 4;
    const int r16  = lane & 15;

    const int srow = w * 32;                       // wave stages 32 rows
    const int lrow = lane >> 3;                    // 0..7 within 8-row group
    const int lxor = (((lane & 7) ^ lrow) * 8);    // permuted k-offset (shorts)

    f32x4 acc[4][4] = {};

    for (int k0 = 0; k0 < HID_SZ; k0 += 64) {
        __syncthreads();   // prev iter's ds_reads done before overwrite
#pragma unroll
        for (int j = 0; j < 4; ++j) {
            const int row = srow + j * 8 + lrow;
            gload16(&X[(size_t)(m0 + row) * HID_SZ + k0 + lxor],
                    &As[(srow + j * 8) * 64]);
            gload16(&W[(size_t)(c0 + row) * HID_SZ + k0 + lxor],
                    &Bs[(srow + j * 8) * 64]);
        }
        __syncthreads();   // staging drained

#pragma unroll
        for (int kk = 0; kk < 2; ++kk) {
            bf16x8 af[4], bfr[4];
#pragma unroll
            for (int mi = 0; mi < 4; ++mi)
                af[mi] = *(const bf16x8*)&As[(wm + mi * 16 + r16) * 64
                                             + (((kk * 4 + q4) ^ (r16 & 7)) * 8)];
#pragma unroll
            for (int ni = 0; ni < 4; ++ni)
                bfr[ni] = *(const bf16x8*)&Bs[(wn + ni * 16 + r16) * 64
                                              + (((kk * 4 + q4) ^ (r16 & 7)) * 8)];
#pragma unroll
            for (int mi = 0; mi < 4; ++mi)
#pragma unroll
                for (int ni = 0; ni < 4; ++ni)
                    acc[mi][ni] = MFMA16(af[mi], bfr[ni], acc[mi][ni]);
        }
    }

#pragma unroll
    for (int mi = 0; mi < 4; ++mi)
#pragma unroll
    for (int ni = 0; ni < 4; ++ni)
#pragma unroll
    for (int r = 0; r < 4; ++r) {
        const int m = m0 + wm + mi * 16 + q4 * 4 + r;
        const int c = c0 + wn + ni * 16 + r16;
        const float v = acc[mi][ni][r];
        if (proj == 0) {
            qbuf[(size_t)m * HID_SZ + c] = f2bf(v * SLOG2E);
        } else if (proj == 1) {
            kbuf[(size_t)m * HID_SZ + c] = f2bf(v);
        } else {
            const int bb = m >> 11, n = m & (N_SZ - 1);
            const int hh = c >> 6, d = c & 63;
            const int np = (n & ~63) | (((n & 15) << 2) | ((n >> 4) & 3));
            vT[((size_t)((bb * NHEADS + hh) * 64 + d)) * N_SZ + np] = f2bf(v);
        }
    }
}

// ---------------------------------------------------------------------------
// Differential flash attention chunk: prefetch next K, QK on current K,
// raw-v_exp_f32 softmax (no max), perm-packed P -> wave-private LDS,
// PV + l accumulated via MFMA against a ones fragment. No barriers.
// ---------------------------------------------------------------------------
static __device__ __forceinline__ void attn_chunk(
    int n0, int nn,
    const short* __restrict__ kbase, const short* __restrict__ vbase,
    short* __restrict__ P,
    bf16x8 aq1, bf16x8 aq2, bf16x8 ones,
    bf16x8* kc1, bf16x8* kc2, bf16x8* kn1, bf16x8* kn2,
    f32x4* o0, f32x4* o1, f32x4& l0a, f32x4& l1a,
    int q4, int r16, int wg_half, int wlo)
{
    // next-chunk K prefetch (consumed next call)
#pragma unroll
    for (int s = 0; s < 4; ++s) {
        const short* krow = kbase + (size_t)(nn + s * 16 + r16) * HID_SZ;
        kn1[s] = *(const bf16x8*)(krow + q4 * 8);
        kn2[s] = *(const bf16x8*)(krow + 32 + q4 * 8);
    }

    // QK on resident registers
    const f32x4 zz = {0.f, 0.f, 0.f, 0.f};
    f32x4 s0[4], s1[4];
#pragma unroll
    for (int s = 0; s < 4; ++s) {
        s0[s] = MFMA16(aq1, kc1[s], zz);
        s1[s] = MFMA16(aq2, kc2[s], zz);
    }

    // current-chunk V loads (used at PV, ~300+ cyc later)
    bf16x8 vfr[2][4];
#pragma unroll
    for (int kk = 0; kk < 2; ++kk)
#pragma unroll
        for (int d = 0; d < 4; ++d)
            vfr[kk][d] = *(const bf16x8*)(vbase + (size_t)(d * 16 + r16) * N_SZ
                                          + n0 + kk * 32 + q4 * 8);

    // exp2 + pack + wave-private LDS stage (Q pre-scaled to log2 domain)
#pragma unroll
    for (int r = 0; r < 4; ++r) {
        const int row = q4 * 4 + r;
        const int wo  = row * 64 + ((wg_half ^ (row & 7)) << 3) + wlo;
        u32x2 pw;
        pw[0] = pk2(fexp2(s0[0][r]), fexp2(s0[1][r]));
        pw[1] = pk2(fexp2(s0[2][r]), fexp2(s0[3][r]));
        *(u32x2*)&P[wo] = pw;
        pw[0] = pk2(fexp2(s1[0][r]), fexp2(s1[1][r]));
        pw[1] = pk2(fexp2(s1[2][r]), fexp2(s1[3][r]));
        *(u32x2*)&P[1024 + wo] = pw;
    }

    // PV + l (row-sum via ones fragment)
#pragma unroll
    for (int kk = 0; kk < 2; ++kk) {
        const int ro = r16 * 64 + (((kk * 4 + q4) ^ (r16 & 7)) << 3);
        bf16x8 ap0 = *(const bf16x8*)&P[ro];
        bf16x8 ap1 = *(const bf16x8*)&P[1024 + ro];
        l0a = MFMA16(ap0, ones, l0a);
        l1a = MFMA16(ap1, ones, l1a);
#pragma unroll
        for (int d = 0; d < 4; ++d) {
            o0[d] = MFMA16(ap0, vfr[kk][d], o0[d]);
            o1[d] = MFMA16(ap1, vfr[kk][d], o1[d]);
        }
    }
}

// 1D grid 1024, XCD-swizzled; 256 thr = 4 waves; wave w owns 16 t-rows.
__global__ __launch_bounds__(256, 4) void attn_kernel(
    const short* __restrict__ qbuf, const short* __restrict__ kbuf,
    const short* __restrict__ vT,
    const float* __restrict__ lq1, const float* __restrict__ lq2,
    const float* __restrict__ lk1, const float* __restrict__ lk2,
    float* __restrict__ out)
{
    const int bi   = blockIdx.x;
    const int work = (bi & 7) * 128 + (bi >> 3);   // XCD-contiguous work id
    const int t0   = (work & 31) * 64;
    const int hb   = work >> 5;
    const int h    = hb & 15;
    const int b    = hb >> 4;

    const int tid = threadIdx.x;
    const int w    = tid >> 6;
    const int lane = tid & 63;
    const int q4   = lane >> 4;
    const int r16  = lane & 15;

    float d1 = 0.f, d2 = 0.f;
#pragma unroll
    for (int i = 0; i < 32; ++i) { d1 += lq1[i] * lk1[i]; d2 += lq2[i] * lk2[i]; }
    const float lam = __expf(d1) - __expf(d2) + 0.8f;

    __shared__ short Pl[4][2 * 16 * 64];
    short* __restrict__ P = &Pl[w][0];

    const int trow = t0 + w * 16 + r16;
    const short* qrow = qbuf + ((size_t)(b * T_SZ + trow)) * HID_SZ + h * 64;
    const bf16x8 aq1 = *(const bf16x8*)(qrow + q4 * 8);
    const bf16x8 aq2 = *(const bf16x8*)(qrow + 32 + q4 * 8);

    const short* kbase = kbuf + (size_t)b * N_SZ * HID_SZ + h * 64;
    const short* vbase = vT + ((size_t)(b * NHEADS + h)) * 64 * N_SZ;

    bf16x8 ones;
#pragma unroll
    for (int i = 0; i < 8; ++i) ones[i] = (short)0x3F80;   // bf16 1.0

    f32x4 o0[4] = {}, o1[4] = {};
    f32x4 l0a = {0.f, 0.f, 0.f, 0.f}, l1a = {0.f, 0.f, 0.f, 0.f};

    const int wg_half = (r16 >> 1);
    const int wlo     = (r16 & 1) * 4;

    // prefetch K chunk 0 into buffer A
    bf16x8 kA1[4], kA2[4], kB1[4], kB2[4];
#pragma unroll
    for (int s = 0; s < 4; ++s) {
        const short* krow = kbase + (size_t)(s * 16 + r16) * HID_SZ;
        kA1[s] = *(const bf16x8*)(krow + q4 * 8);
        kA2[s] = *(const bf16x8*)(krow + 32 + q4 * 8);
    }

    for (int n0 = 0; n0 < N_SZ; n0 += 128) {
        attn_chunk(n0, n0 + 64, kbase, vbase, P, aq1, aq2, ones,
                   kA1, kA2, kB1, kB2, o0, o1, l0a, l1a,
                   q4, r16, wg_half, wlo);
        attn_chunk(n0 + 64, (n0 + 128) & (N_SZ - 1), kbase, vbase, P,
                   aq1, aq2, ones, kB1, kB2, kA1, kA2, o0, o1, l0a, l1a,
                   q4, r16, wg_half, wlo);
    }

    float rl0[4], rl1[4];
#pragma unroll
    for (int r = 0; r < 4; ++r) { rl0[r] = 1.f / l0a[r]; rl1[r] = lam / l1a[r]; }

#pragma unroll
    for (int d = 0; d < 4; ++d)
#pragma unroll
        for (int r = 0; r < 4; ++r) {
            const int t  = t0 + w * 16 + q4 * 4 + r;
            const int vd = d * 16 + r16;
            out[((size_t)(b * T_SZ + t)) * HID_SZ + h * 64 + vd] =
                o0[d][r] * rl0[r] - o1[d][r] * rl1[r];
        }
}

extern "C" void kernel_launch(void* const* d_in, const int* in_sizes, int n_in,
                              void* d_out, int out_size, void* d_ws, size_t ws_size,
                              hipStream_t stream)
{
    (void)in_sizes; (void)n_in; (void)out_size; (void)ws_size;

    const float* enc = (const float*)d_in[0];
    const float* dec = (const float*)d_in[1];
    const float* Wq  = (const float*)d_in[2];
    const float* Wk  = (const float*)d_in[3];
    const float* Wv  = (const float*)d_in[4];
    const float* lq1 = (const float*)d_in[5];
    const float* lq2 = (const float*)d_in[6];
    const float* lk1 = (const float*)d_in[7];
    const float* lk2 = (const float*)d_in[8];
    float* out = (float*)d_out;

    short* qbuf = (short*)d_ws;                          // [4096,1024]
    short* kbuf = qbuf + (size_t)4096 * 1024;            // [4096,1024]
    short* vT   = kbuf + (size_t)4096 * 1024;            // [B,H,64,2048]
    short* decb = vT   + (size_t)4096 * 1024;            // [2,2048,1024]
    short* encb = decb + (size_t)2 * 2048 * 1024;        // [2,2048,1024]
    short* wqb  = encb + (size_t)2 * 2048 * 1024;        // [1024,1024]
    short* wkb  = wqb  + (size_t)1024 * 1024;
    short* wvb  = wkb  + (size_t)1024 * 1024;

    cvt_kernel<<<dim3(2048, 5), 256, 0, stream>>>(
        dec, enc, Wq, Wk, Wv, decb, encb, wqb, wkb, wvb);

    proj_kernel<<<768, 256, 0, stream>>>(
        decb, encb, wqb, wkb, wvb, qbuf, kbuf, vT);

    attn_kernel<<<1024, 256, 0, stream>>>(
        qbuf, kbuf, vT, lq1, lq2, lk1, lk2, out);
}

// Round 6
// 245.728 us; speedup vs baseline: 1.6637x; 1.6637x over previous
//
#include <hip/hip_runtime.h>

typedef short bf16x8 __attribute__((ext_vector_type(8)));
typedef float f32x4  __attribute__((ext_vector_type(4)));
typedef unsigned int u32x2 __attribute__((ext_vector_type(2)));

#define B_SZ   2
#define T_SZ   2048
#define N_SZ   2048
#define HID_SZ 1024
#define NHEADS 16

// scale/sqrt(half) * log2(e), folded into Q at projection epilogue
#define SLOG2E 0.25500297f

static __device__ __forceinline__ float fexp2(float x) {
#if __has_builtin(__builtin_amdgcn_exp2f)
    return __builtin_amdgcn_exp2f(x);       // raw v_exp_f32
#else
    float r; __asm__("v_exp_f32 %0, %1" : "=v"(r) : "v"(x)); return r;
#endif
}

static __device__ __forceinline__ short f2bf(float f) {
    unsigned u = __float_as_uint(f);
    u = (u + 0x7fffu + ((u >> 16) & 1u)) >> 16;   // RNE
    return (short)u;
}

// pack two floats -> two bf16 (round-half-up) via v_perm_b32
static __device__ __forceinline__ unsigned pk2(float a, float b) {
#if __has_builtin(__builtin_amdgcn_perm)
    return __builtin_amdgcn_perm(__float_as_uint(b) + 0x8000u,
                                 __float_as_uint(a) + 0x8000u, 0x07060302u);
#else
    unsigned ua = (__float_as_uint(a) + 0x8000u) >> 16;
    unsigned ub = (__float_as_uint(b) + 0x8000u) & 0xffff0000u;
    return ua | ub;
#endif
}

// async global->LDS, 16B per lane; LDS dest = wave-uniform base + lane*16
static __device__ __forceinline__ void gload16(const void* g, void* l) {
    __builtin_amdgcn_global_load_lds(
        (const __attribute__((address_space(1))) unsigned int*)g,
        (__attribute__((address_space(3))) unsigned int*)l, 16, 0, 0);
}

#define MFMA16(a, b, c) __builtin_amdgcn_mfma_f32_16x16x32_bf16((a), (b), (c), 0, 0, 0)

// ---------------------------------------------------------------------------
// fp32 -> bf16 pre-convert (RNE), 8 elem/thread.
// ---------------------------------------------------------------------------
__global__ __launch_bounds__(256) void cvt_kernel(
    const float* __restrict__ dec, const float* __restrict__ enc,
    const float* __restrict__ Wq, const float* __restrict__ Wk,
    const float* __restrict__ Wv,
    short* __restrict__ decb, short* __restrict__ encb,
    short* __restrict__ wqb, short* __restrict__ wkb, short* __restrict__ wvb)
{
    const float* src; short* dst; int n;
    switch (blockIdx.y) {
      case 0: src = dec; dst = decb; n = B_SZ * T_SZ * HID_SZ; break;
      case 1: src = enc; dst = encb; n = B_SZ * N_SZ * HID_SZ; break;
      case 2: src = Wq;  dst = wqb;  n = HID_SZ * HID_SZ;      break;
      case 3: src = Wk;  dst = wkb;  n = HID_SZ * HID_SZ;      break;
      default:src = Wv;  dst = wvb;  n = HID_SZ * HID_SZ;      break;
    }
    const int idx = (blockIdx.x * 256 + threadIdx.x) * 8;
    if (idx >= n) return;
    float4 a = *(const float4*)&src[idx];
    float4 b = *(const float4*)&src[idx + 4];
    bf16x8 r;
    r[0]=f2bf(a.x); r[1]=f2bf(a.y); r[2]=f2bf(a.z); r[3]=f2bf(a.w);
    r[4]=f2bf(b.x); r[5]=f2bf(b.y); r[6]=f2bf(b.z); r[7]=f2bf(b.w);
    *(bf16x8*)&dst[idx] = r;
}

// ---------------------------------------------------------------------------
// Projection GEMM, m97 structure + XOR-swizzled LDS staging.
// 128x128 tile, BK=64, 256 thr = 4 waves (2x2), 64x64/wave.
// Outputs:
//  proj 0: qbuf [4096,1024] row-major bf16, pre-scaled by SLOG2E
//  proj 1: kblk [(b*16+h)*32+nc][64 n][8 kg][8] — per-chunk 8KB contiguous,
//          kg stored at (kg ^ (n&7)) (bank swizzle baked into layout)
//  proj 2: vblk [(b*16+h)*32+nc][64 vd][8 ng][8] — n' = (n&15)*4+((n>>4)&3),
//          ng stored at (ng ^ (vd&7))
// ---------------------------------------------------------------------------
__global__ __launch_bounds__(256) void proj_kernel(
    const short* __restrict__ decb, const short* __restrict__ encb,
    const short* __restrict__ wqb, const short* __restrict__ wkb,
    const short* __restrict__ wvb,
    short* __restrict__ qbuf, short* __restrict__ kblk, short* __restrict__ vblk)
{
    const int i    = blockIdx.x;
    const int work = (i & 7) * 96 + (i >> 3);     // XCD-contiguous work id
    const int proj = work >> 8;
    const int rem  = work & 255;
    const int c0   = (rem >> 5) * 128;
    const int m0   = (rem & 31) * 128;

    const short* __restrict__ X = (proj == 0) ? decb : encb;
    const short* __restrict__ W = (proj == 0) ? wqb : ((proj == 1) ? wkb : wvb);

    __shared__ short As[128 * 64];   // 16 KB
    __shared__ short Bs[128 * 64];   // 16 KB

    const int tid  = threadIdx.x;
    const int lane = tid & 63;
    const int w    = tid >> 6;
    const int wm   = (w >> 1) * 64;
    const int wn   = (w & 1) * 64;
    const int q4   = lane >> 4;
    const int r16  = lane & 15;

    const int srow = w * 32;                       // wave stages 32 rows
    const int lrow = lane >> 3;                    // 0..7 within 8-row group
    const int lxor = (((lane & 7) ^ lrow) * 8);    // permuted k-offset (shorts)

    f32x4 acc[4][4] = {};

    for (int k0 = 0; k0 < HID_SZ; k0 += 64) {
        __syncthreads();   // prev iter's ds_reads done before overwrite
#pragma unroll
        for (int j = 0; j < 4; ++j) {
            const int row = srow + j * 8 + lrow;
            gload16(&X[(size_t)(m0 + row) * HID_SZ + k0 + lxor],
                    &As[(srow + j * 8) * 64]);
            gload16(&W[(size_t)(c0 + row) * HID_SZ + k0 + lxor],
                    &Bs[(srow + j * 8) * 64]);
        }
        __syncthreads();   // staging drained

#pragma unroll
        for (int kk = 0; kk < 2; ++kk) {
            bf16x8 af[4], bfr[4];
#pragma unroll
            for (int mi = 0; mi < 4; ++mi)
                af[mi] = *(const bf16x8*)&As[(wm + mi * 16 + r16) * 64
                                             + (((kk * 4 + q4) ^ (r16 & 7)) * 8)];
#pragma unroll
            for (int ni = 0; ni < 4; ++ni)
                bfr[ni] = *(const bf16x8*)&Bs[(wn + ni * 16 + r16) * 64
                                              + (((kk * 4 + q4) ^ (r16 & 7)) * 8)];
#pragma unroll
            for (int mi = 0; mi < 4; ++mi)
#pragma unroll
                for (int ni = 0; ni < 4; ++ni)
                    acc[mi][ni] = MFMA16(af[mi], bfr[ni], acc[mi][ni]);
        }
    }

#pragma unroll
    for (int mi = 0; mi < 4; ++mi)
#pragma unroll
    for (int ni = 0; ni < 4; ++ni)
#pragma unroll
    for (int r = 0; r < 4; ++r) {
        const int m = m0 + wm + mi * 16 + q4 * 4 + r;
        const int c = c0 + wn + ni * 16 + r16;
        const float v = acc[mi][ni][r];
        if (proj == 0) {
            qbuf[(size_t)m * HID_SZ + c] = f2bf(v * SLOG2E);
        } else {
            const int bb = m >> 11, n = m & (N_SZ - 1);
            const int hh = c >> 6;
            const int nc = n >> 6;
            const size_t base = ((size_t)((bb * NHEADS + hh) * 32 + nc)) * 4096;
            if (proj == 1) {
                const int row = n & 63, kd = c & 63;
                const int g = kd >> 3, e = kd & 7;
                kblk[base + row * 64 + (((g ^ (row & 7)) << 3) | e)] = f2bf(v);
            } else {
                const int vd = c & 63, nl = n & 63;
                const int np = ((nl & 15) << 2) | ((nl >> 4) & 3);
                const int g = np >> 3, e = np & 7;
                vblk[base + vd * 64 + (((g ^ (vd & 7)) << 3) | e)] = f2bf(v);
            }
        }
    }
}

// ---------------------------------------------------------------------------
// Differential flash attention, m97-style cooperative staging:
// per 64-n chunk, the block DMA-stages the contiguous 8KB K-blob + 8KB V-blob
// into LDS (global_load_lds, barrier-synced); all 4 waves read fragments from
// LDS (swizzle-baked, conflict-free). Softmax: raw v_exp_f32, no max
// (Q pre-scaled to log2 domain), l via MFMA-ones. P wave-private in LDS.
// 1D grid 1024, XCD-swizzled.
// ---------------------------------------------------------------------------
__global__ __launch_bounds__(256) void attn_kernel(
    const short* __restrict__ qbuf, const short* __restrict__ kblk,
    const short* __restrict__ vblk,
    const float* __restrict__ lq1, const float* __restrict__ lq2,
    const float* __restrict__ lk1, const float* __restrict__ lk2,
    float* __restrict__ out)
{
    const int bi   = blockIdx.x;
    const int work = (bi & 7) * 128 + (bi >> 3);   // XCD-contiguous work id
    const int t0   = (work & 31) * 64;
    const int hb   = work >> 5;
    const int h    = hb & 15;
    const int b    = hb >> 4;

    const int tid = threadIdx.x;
    const int w    = tid >> 6;
    const int lane = tid & 63;
    const int q4   = lane >> 4;
    const int r16  = lane & 15;

    float d1 = 0.f, d2 = 0.f;
#pragma unroll
    for (int i = 0; i < 32; ++i) { d1 += lq1[i] * lk1[i]; d2 += lq2[i] * lk2[i]; }
    const float lam = __expf(d1) - __expf(d2) + 0.8f;

    __shared__ short Ks[4096];        // 8 KB staged K chunk
    __shared__ short Vs[4096];        // 8 KB staged V chunk
    __shared__ short Pl[4][2048];     // per-wave P (2 comps x 16 x 64)
    short* __restrict__ P = &Pl[w][0];

    const int trow = t0 + w * 16 + r16;
    const short* qrow = qbuf + ((size_t)(b * T_SZ + trow)) * HID_SZ + h * 64;
    const bf16x8 aq1 = *(const bf16x8*)(qrow + q4 * 8);
    const bf16x8 aq2 = *(const bf16x8*)(qrow + 32 + q4 * 8);

    const short* kbh = kblk + ((size_t)(b * NHEADS + h)) * 32 * 4096;
    const short* vbh = vblk + ((size_t)(b * NHEADS + h)) * 32 * 4096;

    bf16x8 ones;
#pragma unroll
    for (int i = 0; i < 8; ++i) ones[i] = (short)0x3F80;   // bf16 1.0

    f32x4 o0[4] = {}, o1[4] = {};
    f32x4 l0a = {0.f, 0.f, 0.f, 0.f}, l1a = {0.f, 0.f, 0.f, 0.f};

    const int wg_half = (r16 >> 1);
    const int wlo     = (r16 & 1) * 4;
    const int swz     = r16 & 7;      // fragment-read unswizzle

    for (int nc = 0; nc < 32; ++nc) {
        const short* Kg = kbh + nc * 4096;
        const short* Vg = vbh + nc * 4096;

        __syncthreads();   // all waves done reading previous chunk's Ks/Vs
#pragma unroll
        for (int j = 0; j < 2; ++j) {
            gload16(&Kg[(w * 2 + j) * 512 + lane * 8], &Ks[(w * 2 + j) * 512]);
            gload16(&Vg[(w * 2 + j) * 512 + lane * 8], &Vs[(w * 2 + j) * 512]);
        }
        __syncthreads();   // staging drained (vmcnt before barrier)

        // QK from LDS
        const f32x4 zz = {0.f, 0.f, 0.f, 0.f};
        f32x4 s0[4], s1[4];
#pragma unroll
        for (int s = 0; s < 4; ++s) {
            const int row = s * 16 + r16;
            bf16x8 bk1 = *(const bf16x8*)&Ks[row * 64 + ((q4 ^ swz) << 3)];
            bf16x8 bk2 = *(const bf16x8*)&Ks[row * 64 + (((4 + q4) ^ swz) << 3)];
            s0[s] = MFMA16(aq1, bk1, zz);
            s1[s] = MFMA16(aq2, bk2, zz);
        }

        // exp2 + pack + wave-private LDS stage
#pragma unroll
        for (int r = 0; r < 4; ++r) {
            const int row = q4 * 4 + r;
            const int wo  = row * 64 + ((wg_half ^ (row & 7)) << 3) + wlo;
            u32x2 pw;
            pw[0] = pk2(fexp2(s0[0][r]), fexp2(s0[1][r]));
            pw[1] = pk2(fexp2(s0[2][r]), fexp2(s0[3][r]));
            *(u32x2*)&P[wo] = pw;
            pw[0] = pk2(fexp2(s1[0][r]), fexp2(s1[1][r]));
            pw[1] = pk2(fexp2(s1[2][r]), fexp2(s1[3][r]));
            *(u32x2*)&P[1024 + wo] = pw;
        }

        // PV + l from LDS
#pragma unroll
        for (int kk = 0; kk < 2; ++kk) {
            const int ro = r16 * 64 + (((kk * 4 + q4) ^ swz) << 3);
            bf16x8 ap0 = *(const bf16x8*)&P[ro];
            bf16x8 ap1 = *(const bf16x8*)&P[1024 + ro];
            l0a = MFMA16(ap0, ones, l0a);
            l1a = MFMA16(ap1, ones, l1a);
#pragma unroll
            for (int d = 0; d < 4; ++d) {
                const int vd = d * 16 + r16;
                bf16x8 bv = *(const bf16x8*)&Vs[vd * 64 + (((kk * 4 + q4) ^ swz) << 3)];
                o0[d] = MFMA16(ap0, bv, o0[d]);
                o1[d] = MFMA16(ap1, bv, o1[d]);
            }
        }
    }

    float rl0[4], rl1[4];
#pragma unroll
    for (int r = 0; r < 4; ++r) { rl0[r] = 1.f / l0a[r]; rl1[r] = lam / l1a[r]; }

#pragma unroll
    for (int d = 0; d < 4; ++d)
#pragma unroll
        for (int r = 0; r < 4; ++r) {
            const int t  = t0 + w * 16 + q4 * 4 + r;
            const int vd = d * 16 + r16;
            out[((size_t)(b * T_SZ + t)) * HID_SZ + h * 64 + vd] =
                o0[d][r] * rl0[r] - o1[d][r] * rl1[r];
        }
}

extern "C" void kernel_launch(void* const* d_in, const int* in_sizes, int n_in,
                              void* d_out, int out_size, void* d_ws, size_t ws_size,
                              hipStream_t stream)
{
    (void)in_sizes; (void)n_in; (void)out_size; (void)ws_size;

    const float* enc = (const float*)d_in[0];
    const float* dec = (const float*)d_in[1];
    const float* Wq  = (const float*)d_in[2];
    const float* Wk  = (const float*)d_in[3];
    const float* Wv  = (const float*)d_in[4];
    const float* lq1 = (const float*)d_in[5];
    const float* lq2 = (const float*)d_in[6];
    const float* lk1 = (const float*)d_in[7];
    const float* lk2 = (const float*)d_in[8];
    float* out = (float*)d_out;

    short* qbuf = (short*)d_ws;                          // [4096,1024]
    short* kblk = qbuf + (size_t)4096 * 1024;            // [32 bh][32 nc][4096]
    short* vblk = kblk + (size_t)4096 * 1024;            // [32 bh][32 nc][4096]
    short* decb = vblk + (size_t)4096 * 1024;            // [2,2048,1024]
    short* encb = decb + (size_t)2 * 2048 * 1024;        // [2,2048,1024]
    short* wqb  = encb + (size_t)2 * 2048 * 1024;        // [1024,1024]
    short* wkb  = wqb  + (size_t)1024 * 1024;
    short* wvb  = wkb  + (size_t)1024 * 1024;

    cvt_kernel<<<dim3(2048, 5), 256, 0, stream>>>(
        dec, enc, Wq, Wk, Wv, decb, encb, wqb, wkb, wvb);

    proj_kernel<<<768, 256, 0, stream>>>(
        decb, encb, wqb, wkb, wvb, qbuf, kblk, vblk);

    attn_kernel<<<1024, 256, 0, stream>>>(
        qbuf, kblk, vblk, lq1, lq2, lk1, lk2, out);
}